// Round 1
// baseline (109.404 us; speedup 1.0000x reference)
//
#include <hip/hip_runtime.h>

typedef __attribute__((ext_vector_type(8))) _Float16 half8;
typedef __attribute__((ext_vector_type(4))) float f32x4;

#define NB 2
#define CIN 64
#define ICH 32
#define HH 80
#define WW 80
#define NSP 6400
#define KSPLIT 5
#define KRANGE 1280
#define KBLK 64
#define NITER 20
#define QTILES 200

// ---------------------------------------------------------------------------
// Kernel 1: 3x3 convs (theta on x, phi on x_t) + fused 1x1 g-conv (on x_t).
// Outputs: Q (b,n,32) f16 row-major, K (b,n,32) f16 row-major, Vt (b,32,n) f16.
// grid = 320 blocks (src(2) x b(2) x h(80)), 256 threads.
// ---------------------------------------------------------------------------
__global__ __launch_bounds__(256) void nlb_conv_kernel(
    const float* __restrict__ x, const float* __restrict__ x_t,
    const float* __restrict__ shared_w, const float* __restrict__ shared_b,
    const float* __restrict__ g_w, const float* __restrict__ g_b,
    _Float16* __restrict__ Q, _Float16* __restrict__ K, _Float16* __restrict__ Vt)
{
    const int bid = blockIdx.x;
    const int src = bid & 1;
    const int b   = (bid >> 1) & 1;
    const int h   = bid >> 2;
    const float* __restrict__ in = src ? x_t : x;

    __shared__ float xs[CIN][3][WW + 2];
    __shared__ float gwl[ICH * CIN];

    const int tid = threadIdx.x;

    // stage 3 input rows (zero-padded) for all 64 channels
    for (int e = tid; e < CIN * 3 * WW; e += 256) {
        int c  = e / (3 * WW);
        int rr = (e / WW) % 3;
        int w  = e % WW;
        int hr = h + rr - 1;
        float v = 0.f;
        if (hr >= 0 && hr < HH) v = in[((b * CIN + c) * HH + hr) * WW + w];
        xs[c][rr][w + 1] = v;
    }
    for (int e = tid; e < CIN * 3; e += 256) {
        int c = e / 3, rr = e % 3;
        xs[c][rr][0] = 0.f;
        xs[c][rr][WW + 1] = 0.f;
    }
    if (src) {
        for (int e = tid; e < ICH * CIN; e += 256) gwl[e] = g_w[e];
    }
    __syncthreads();

    const int o  = tid >> 3;   // 0..31 output channel
    const int wg = tid & 7;    // 0..7 -> 10 w positions each
    const int w0 = wg * 10;

    float acc[10], accg[10];
    const float bias = shared_b[o];
    #pragma unroll
    for (int i = 0; i < 10; ++i) { acc[i] = bias; accg[i] = 0.f; }

    const float* __restrict__ wsp = shared_w + o * CIN * 9;

    for (int c = 0; c < CIN; ++c) {
        float wv[9];
        #pragma unroll
        for (int k = 0; k < 9; ++k) wv[k] = wsp[c * 9 + k];
        #pragma unroll
        for (int rr = 0; rr < 3; ++rr) {
            float xr[12];
            #pragma unroll
            for (int dw = 0; dw < 12; ++dw) xr[dw] = xs[c][rr][w0 + dw];
            #pragma unroll
            for (int i = 0; i < 10; ++i)
                acc[i] += xr[i] * wv[rr * 3 + 0] + xr[i + 1] * wv[rr * 3 + 1]
                        + xr[i + 2] * wv[rr * 3 + 2];
            if (src && rr == 1) {
                float gww = gwl[o * CIN + c];
                #pragma unroll
                for (int i = 0; i < 10; ++i) accg[i] += gww * xr[i + 1];
            }
        }
    }

    const int pbase = h * WW + w0;
    if (!src) {
        #pragma unroll
        for (int i = 0; i < 10; ++i)
            Q[(size_t)(b * NSP + pbase + i) * ICH + o] = (_Float16)acc[i];
    } else {
        const float gb = g_b[o];
        #pragma unroll
        for (int i = 0; i < 10; ++i) {
            K[(size_t)(b * NSP + pbase + i) * ICH + o] = (_Float16)acc[i];
            Vt[(size_t)(b * ICH + o) * NSP + pbase + i] = (_Float16)(accg[i] + gb);
        }
    }
}

// ---------------------------------------------------------------------------
// Kernel 2: flash attention, one wave per (batch, 32-row q-tile, k-split).
// grid = 2000 blocks x 64 threads. Writes unnormalized YU + (m,l) per row.
// ---------------------------------------------------------------------------
__global__ __launch_bounds__(64) void nlb_attn_kernel(
    const _Float16* __restrict__ Q, const _Float16* __restrict__ Km,
    const _Float16* __restrict__ Vt,
    float* __restrict__ YU, float* __restrict__ ML)
{
    const int bid = blockIdx.x;
    const int s = bid % KSPLIT;
    const int t = (bid / KSPLIT) % QTILES;
    const int b = bid / (KSPLIT * QTILES);
    const int lane = threadIdx.x;
    const int g = lane >> 4, r = lane & 15;

    __shared__ __align__(16) _Float16 PB[32][72];  // P tile 32q x 64k (+pad)

    const _Float16* __restrict__ Qb = Q  + (size_t)b * NSP * ICH;
    const _Float16* __restrict__ Kb = Km + (size_t)b * NSP * ICH;
    const _Float16* __restrict__ Vb = Vt + (size_t)b * ICH * NSP;

    const f32x4 zero4 = {0.f, 0.f, 0.f, 0.f};

    half8 qa[2];
    #pragma unroll
    for (int qf = 0; qf < 2; ++qf)
        qa[qf] = *(const half8*)(Qb + (size_t)(t * 32 + qf * 16 + r) * ICH + g * 8);

    f32x4 yacc[2][2];
    float m_run[2][4], l_run[2][4];
    #pragma unroll
    for (int qf = 0; qf < 2; ++qf) {
        yacc[qf][0] = zero4; yacc[qf][1] = zero4;
        #pragma unroll
        for (int j = 0; j < 4; ++j) { m_run[qf][j] = -1e30f; l_run[qf][j] = 0.f; }
    }

    const int kbase0 = s * KRANGE;
    for (int it = 0; it < NITER; ++it) {
        const int kb0 = kbase0 + it * KBLK;

        half8 kf[4], vf[2][2];
        #pragma unroll
        for (int kh = 0; kh < 4; ++kh)
            kf[kh] = *(const half8*)(Kb + (size_t)(kb0 + kh * 16 + r) * ICH + g * 8);
        #pragma unroll
        for (int ks = 0; ks < 2; ++ks)
            #pragma unroll
            for (int ch = 0; ch < 2; ++ch)
                vf[ks][ch] = *(const half8*)(Vb + (size_t)(ch * 16 + r) * NSP + kb0 + ks * 32 + g * 8);

        // S = Q K^T  (D-layout: row q = g*4+j, col kpos = r)
        f32x4 sa[2][4];
        #pragma unroll
        for (int qf = 0; qf < 2; ++qf)
            #pragma unroll
            for (int kh = 0; kh < 4; ++kh)
                sa[qf][kh] = __builtin_amdgcn_mfma_f32_16x16x32_f16(qa[qf], kf[kh], zero4, 0, 0, 0);

        // defer-max check (no cross-lane reduce on the fast path)
        float mx = -1e30f;
        #pragma unroll
        for (int qf = 0; qf < 2; ++qf)
            #pragma unroll
            for (int j = 0; j < 4; ++j) {
                float rm = fmaxf(fmaxf(sa[qf][0][j], sa[qf][1][j]),
                                 fmaxf(sa[qf][2][j], sa[qf][3][j]));
                mx = fmaxf(mx, rm - m_run[qf][j]);
            }
        if (__any(mx > 8.f)) {   // slow path: true row-max update + rescale
            #pragma unroll
            for (int qf = 0; qf < 2; ++qf)
                #pragma unroll
                for (int j = 0; j < 4; ++j) {
                    float tm = fmaxf(fmaxf(sa[qf][0][j], sa[qf][1][j]),
                                     fmaxf(sa[qf][2][j], sa[qf][3][j]));
                    tm = fmaxf(tm, __shfl_xor(tm, 1));
                    tm = fmaxf(tm, __shfl_xor(tm, 2));
                    tm = fmaxf(tm, __shfl_xor(tm, 4));
                    tm = fmaxf(tm, __shfl_xor(tm, 8));
                    float mn = fmaxf(m_run[qf][j], tm);
                    float sc = __expf(m_run[qf][j] - mn);
                    l_run[qf][j] *= sc;
                    yacc[qf][0][j] *= sc;
                    yacc[qf][1][j] *= sc;
                    m_run[qf][j] = mn;
                }
        }

        // P = exp(S - m), per-lane l accumulation, stage P tile to LDS
        #pragma unroll
        for (int qf = 0; qf < 2; ++qf)
            #pragma unroll
            for (int kh = 0; kh < 4; ++kh)
                #pragma unroll
                for (int j = 0; j < 4; ++j) {
                    float p = __expf(sa[qf][kh][j] - m_run[qf][j]);
                    l_run[qf][j] += p;
                    PB[qf * 16 + g * 4 + j][kh * 16 + r] = (_Float16)p;
                }
        __syncthreads();

        // PV: y += P V
        #pragma unroll
        for (int ks = 0; ks < 2; ++ks) {
            half8 pa[2];
            #pragma unroll
            for (int qf = 0; qf < 2; ++qf)
                pa[qf] = *(const half8*)(&PB[qf * 16 + r][ks * 32 + g * 8]);
            #pragma unroll
            for (int qf = 0; qf < 2; ++qf)
                #pragma unroll
                for (int ch = 0; ch < 2; ++ch)
                    yacc[qf][ch] = __builtin_amdgcn_mfma_f32_16x16x32_f16(
                        pa[qf], vf[ks][ch], yacc[qf][ch], 0, 0, 0);
        }
        __syncthreads();
    }

    // final row-sum reduce of l across the 16 lanes of each group
    #pragma unroll
    for (int qf = 0; qf < 2; ++qf)
        #pragma unroll
        for (int j = 0; j < 4; ++j) {
            float lv = l_run[qf][j];
            lv += __shfl_xor(lv, 1);
            lv += __shfl_xor(lv, 2);
            lv += __shfl_xor(lv, 4);
            lv += __shfl_xor(lv, 8);
            l_run[qf][j] = lv;
        }

    if (r == 0) {
        #pragma unroll
        for (int qf = 0; qf < 2; ++qf)
            #pragma unroll
            for (int j = 0; j < 4; ++j) {
                int row = t * 32 + qf * 16 + g * 4 + j;
                size_t base = ((size_t)(s * NB + b) * NSP + row) * 2;
                ML[base + 0] = m_run[qf][j];
                ML[base + 1] = l_run[qf][j];
            }
    }
    #pragma unroll
    for (int qf = 0; qf < 2; ++qf)
        #pragma unroll
        for (int ch = 0; ch < 2; ++ch)
            #pragma unroll
            for (int j = 0; j < 4; ++j) {
                int row = t * 32 + qf * 16 + g * 4 + j;
                YU[((size_t)(s * NB + b) * NSP + row) * ICH + ch * 16 + r] = yacc[qf][ch][j];
            }
}

// ---------------------------------------------------------------------------
// Kernel 3: combine k-splits, normalize, fused W 1x1 projection + bias + residual.
// grid = 200 blocks (b(2) x 100 row-groups of 64), 256 threads.
// ---------------------------------------------------------------------------
__global__ __launch_bounds__(256) void nlb_combine_kernel(
    const float* __restrict__ YU, const float* __restrict__ ML,
    const float* __restrict__ W_w, const float* __restrict__ W_b,
    const float* __restrict__ x, float* __restrict__ out)
{
    const int bid = blockIdx.x;
    const int b = bid / 100;
    const int rowbase = (bid % 100) * 64;

    __shared__ float ylds[64][33];
    __shared__ float wwl[CIN * ICH];

    const int tid = threadIdx.x;
    for (int e = tid; e < CIN * ICH; e += 256) wwl[e] = W_w[e];

    #pragma unroll
    for (int i = 0; i < 8; ++i) {
        int idx = tid + i * 256;          // 0..2047 -> (row, c)
        int row = idx >> 5, c = idx & 31;
        int grow = rowbase + row;
        float m[KSPLIT], lv[KSPLIT], M = -1e30f;
        #pragma unroll
        for (int s2 = 0; s2 < KSPLIT; ++s2) {
            size_t base = ((size_t)(s2 * NB + b) * NSP + grow) * 2;
            m[s2]  = ML[base + 0];
            lv[s2] = ML[base + 1];
            M = fmaxf(M, m[s2]);
        }
        float denom = 0.f, acc = 0.f;
        #pragma unroll
        for (int s2 = 0; s2 < KSPLIT; ++s2) {
            float e2 = __expf(m[s2] - M);
            denom += lv[s2] * e2;
            acc += YU[((size_t)(s2 * NB + b) * NSP + grow) * ICH + c] * e2;
        }
        ylds[row][c] = acc / denom;
    }
    __syncthreads();

    const int row = tid & 63;
    const int o0  = tid >> 6;             // 0..3
    #pragma unroll
    for (int k = 0; k < 16; ++k) {
        int o = o0 * 16 + k;
        size_t gi = (size_t)(b * CIN + o) * NSP + rowbase + row;
        float accv = W_b[o] + x[gi];
        #pragma unroll
        for (int c = 0; c < ICH; ++c) accv += wwl[o * ICH + c] * ylds[row][c];
        out[gi] = accv;
    }
}

// ---------------------------------------------------------------------------
extern "C" void kernel_launch(void* const* d_in, const int* in_sizes, int n_in,
                              void* d_out, int out_size, void* d_ws, size_t ws_size,
                              hipStream_t stream) {
    const float* x        = (const float*)d_in[0];
    const float* x_t      = (const float*)d_in[1];
    const float* g_w      = (const float*)d_in[2];
    const float* g_b      = (const float*)d_in[3];
    const float* W_w      = (const float*)d_in[4];
    const float* W_b      = (const float*)d_in[5];
    const float* shared_w = (const float*)d_in[6];
    const float* shared_b = (const float*)d_in[7];
    float* out = (float*)d_out;

    char* ws = (char*)d_ws;
    _Float16* Q  = (_Float16*)(ws);                    //   819,200 B
    _Float16* K  = (_Float16*)(ws + 819200);           //   819,200 B
    _Float16* Vt = (_Float16*)(ws + 1638400);          //   819,200 B
    float*    YU = (float*)(ws + 2457600);             // 8,192,000 B
    float*    ML = (float*)(ws + 10649600);            //   512,000 B  (~10.6 MB total)

    hipLaunchKernelGGL(nlb_conv_kernel, dim3(320), dim3(256), 0, stream,
                       x, x_t, shared_w, shared_b, g_w, g_b, Q, K, Vt);
    hipLaunchKernelGGL(nlb_attn_kernel, dim3(2000), dim3(64), 0, stream,
                       Q, K, Vt, YU, ML);
    hipLaunchKernelGGL(nlb_combine_kernel, dim3(200), dim3(256), 0, stream,
                       YU, ML, W_w, W_b, x, out);
}

// Round 2
// 81.633 us; speedup vs baseline: 1.3402x; 1.3402x over previous
//
#include <hip/hip_runtime.h>

typedef __attribute__((ext_vector_type(8))) _Float16 half8;
typedef __attribute__((ext_vector_type(4))) _Float16 half4;
typedef __attribute__((ext_vector_type(4))) float f32x4;

#define NB 2
#define CIN 64
#define ICH 32
#define HH 80
#define WW 80
#define NSP 6400
#define KSPLIT 5
#define KRANGE 1280
#define KBLK 64
#define NITER 20
#define QTILES 200

// ---------------------------------------------------------------------------
// Kernel 0: weight prep. W9f[tap][o][c] f16 from shared_w (o,c,3,3) f32,
// GWf[o][c] f16 from g_w. grid = 80 x 256 covers 18432 + 2048 elements.
// ---------------------------------------------------------------------------
__global__ __launch_bounds__(256) void nlb_prep_kernel(
    const float* __restrict__ shared_w, const float* __restrict__ g_w,
    _Float16* __restrict__ W9f, _Float16* __restrict__ GWf)
{
    int e = blockIdx.x * 256 + threadIdx.x;
    if (e < 9 * 32 * 64) {
        int c = e & 63, o = (e >> 6) & 31, tap = e >> 11;
        W9f[e] = (_Float16)shared_w[(o * 64 + c) * 9 + tap];
    } else {
        int e2 = e - 9 * 32 * 64;
        GWf[e2] = (_Float16)g_w[e2];
    }
}

// ---------------------------------------------------------------------------
// Kernel 1: implicit-GEMM 3x3 conv via MFMA + fused 1x1 g-conv.
// One block per (src, b, h): stages 3 padded rows (82 wi x 64 c) f16 in LDS,
// channel-contiguous with XOR swizzle. 2 waves: wave w = o-block w*16.
// Each wave: 5 n-tiles x (9 taps x 2 c-halves) MFMA 16x16x32 f16.
// ---------------------------------------------------------------------------
__global__ __launch_bounds__(128) void nlb_conv_mfma_kernel(
    const float* __restrict__ x, const float* __restrict__ x_t,
    const _Float16* __restrict__ W9f, const _Float16* __restrict__ GWf,
    const float* __restrict__ shared_b, const float* __restrict__ g_b,
    _Float16* __restrict__ Q, _Float16* __restrict__ K, _Float16* __restrict__ Vt)
{
    const int bid = blockIdx.x;
    const int src = bid & 1;
    const int b   = (bid >> 1) & 1;
    const int h   = bid >> 2;
    const float* __restrict__ in = src ? x_t : x;

    __shared__ _Float16 xs[3 * 82 * 64];   // [row][wi][c] with swizzled 16B slots

    const int tid = threadIdx.x;

    // ---- stage: coalesced global reads (8 w per thread), swizzled f16 writes
    #pragma unroll
    for (int i = 0; i < 15; ++i) {
        int idx = tid + i * 128;          // (rr, c, wc): 3*64*10 = 1920
        int wc = idx % 10;
        int c  = (idx / 10) & 63;
        int rr = idx / 640;
        int hr = h + rr - 1;
        float4 v0 = make_float4(0.f, 0.f, 0.f, 0.f), v1 = v0;
        if (hr >= 0 && hr < HH) {
            const float4* p = (const float4*)(in + ((size_t)(b * CIN + c) * HH + hr) * WW + wc * 8);
            v0 = p[0]; v1 = p[1];
        }
        float vals[8] = {v0.x, v0.y, v0.z, v0.w, v1.x, v1.y, v1.z, v1.w};
        const int cb = c >> 3, cl = c & 7;
        #pragma unroll
        for (int k = 0; k < 8; ++k) {
            int wi = wc * 8 + k + 1;
            int slot = cb ^ ((wi + (wi >> 3)) & 7);
            xs[(rr * 82 + wi) * 64 + slot * 8 + cl] = (_Float16)vals[k];
        }
    }
    // zero-pad wi = 0 and wi = 81
    for (int e = tid; e < 384; e += 128) {
        int wi = (e & 1) ? 81 : 0;
        int rest = e >> 1;
        int c = rest & 63, rr = rest >> 6;
        int slot = (c >> 3) ^ ((wi + (wi >> 3)) & 7);
        xs[(rr * 82 + wi) * 64 + slot * 8 + (c & 7)] = (_Float16)0.f;
    }
    __syncthreads();

    const int wid  = tid >> 6;
    const int lane = tid & 63;
    const int g = lane >> 4, r = lane & 15;
    const int o0 = wid * 16;

    // A fragments: W9f[tap][o0+r][ch*32 + g*8 ..+7]
    half8 aw[9][2];
    #pragma unroll
    for (int tap = 0; tap < 9; ++tap)
        #pragma unroll
        for (int ch = 0; ch < 2; ++ch)
            aw[tap][ch] = *(const half8*)(W9f + ((tap * 32 + o0 + r) * 64 + ch * 32 + g * 8));
    half8 gaf[2];
    if (src) {
        #pragma unroll
        for (int ch = 0; ch < 2; ++ch)
            gaf[ch] = *(const half8*)(GWf + ((o0 + r) * 64 + ch * 32 + g * 8));
    }

    f32x4 biasv, gbv = {0.f, 0.f, 0.f, 0.f};
    #pragma unroll
    for (int j = 0; j < 4; ++j) biasv[j] = shared_b[o0 + g * 4 + j];
    if (src) {
        #pragma unroll
        for (int j = 0; j < 4; ++j) gbv[j] = g_b[o0 + g * 4 + j];
    }

    for (int ti = 0; ti < 5; ++ti) {
        const int n0 = ti * 16;
        const int wi0 = n0 + r;
        f32x4 accE = biasv;
        f32x4 accO = {0.f, 0.f, 0.f, 0.f};
        f32x4 vacc = gbv;
        #pragma unroll
        for (int tap = 0; tap < 9; ++tap) {
            const int kh = tap / 3, kw = tap % 3;
            const int wi = wi0 + kw;
            const int swz = (wi + (wi >> 3)) & 7;
            #pragma unroll
            for (int ch = 0; ch < 2; ++ch) {
                half8 bf = *(const half8*)(&xs[(kh * 82 + wi) * 64 + (((ch * 4 + g) ^ swz) * 8)]);
                if (tap & 1) accO = __builtin_amdgcn_mfma_f32_16x16x32_f16(aw[tap][ch], bf, accO, 0, 0, 0);
                else         accE = __builtin_amdgcn_mfma_f32_16x16x32_f16(aw[tap][ch], bf, accE, 0, 0, 0);
                if (src && tap == 4)
                    vacc = __builtin_amdgcn_mfma_f32_16x16x32_f16(gaf[ch], bf, vacc, 0, 0, 0);
            }
        }
        const int n = h * WW + n0 + r;     // global spatial index
        f32x4 acc;
        #pragma unroll
        for (int j = 0; j < 4; ++j) acc[j] = accE[j] + accO[j];
        half4 pk;
        #pragma unroll
        for (int j = 0; j < 4; ++j) pk[j] = (_Float16)acc[j];
        if (!src) {
            *(half4*)(Q + (size_t)(b * NSP + n) * ICH + o0 + g * 4) = pk;
        } else {
            *(half4*)(K + (size_t)(b * NSP + n) * ICH + o0 + g * 4) = pk;
            #pragma unroll
            for (int j = 0; j < 4; ++j)
                Vt[(size_t)(b * ICH + o0 + g * 4 + j) * NSP + n] = (_Float16)vacc[j];
        }
    }
}

// ---------------------------------------------------------------------------
// Kernel 2: flash attention, one wave per (batch, 32-row q-tile, k-split).
// grid = 2000 blocks x 64 threads. Writes unnormalized YU + (m,l) per row.
// ---------------------------------------------------------------------------
__global__ __launch_bounds__(64) void nlb_attn_kernel(
    const _Float16* __restrict__ Q, const _Float16* __restrict__ Km,
    const _Float16* __restrict__ Vt,
    float* __restrict__ YU, float* __restrict__ ML)
{
    const int bid = blockIdx.x;
    const int s = bid % KSPLIT;
    const int t = (bid / KSPLIT) % QTILES;
    const int b = bid / (KSPLIT * QTILES);
    const int lane = threadIdx.x;
    const int g = lane >> 4, r = lane & 15;

    __shared__ __align__(16) _Float16 PB[32][72];  // P tile 32q x 64k (+pad)

    const _Float16* __restrict__ Qb = Q  + (size_t)b * NSP * ICH;
    const _Float16* __restrict__ Kb = Km + (size_t)b * NSP * ICH;
    const _Float16* __restrict__ Vb = Vt + (size_t)b * ICH * NSP;

    const f32x4 zero4 = {0.f, 0.f, 0.f, 0.f};

    half8 qa[2];
    #pragma unroll
    for (int qf = 0; qf < 2; ++qf)
        qa[qf] = *(const half8*)(Qb + (size_t)(t * 32 + qf * 16 + r) * ICH + g * 8);

    f32x4 yacc[2][2];
    float m_run[2][4], l_run[2][4];
    #pragma unroll
    for (int qf = 0; qf < 2; ++qf) {
        yacc[qf][0] = zero4; yacc[qf][1] = zero4;
        #pragma unroll
        for (int j = 0; j < 4; ++j) { m_run[qf][j] = -1e30f; l_run[qf][j] = 0.f; }
    }

    const int kbase0 = s * KRANGE;
    for (int it = 0; it < NITER; ++it) {
        const int kb0 = kbase0 + it * KBLK;

        half8 kf[4], vf[2][2];
        #pragma unroll
        for (int kh = 0; kh < 4; ++kh)
            kf[kh] = *(const half8*)(Kb + (size_t)(kb0 + kh * 16 + r) * ICH + g * 8);
        #pragma unroll
        for (int ks = 0; ks < 2; ++ks)
            #pragma unroll
            for (int ch = 0; ch < 2; ++ch)
                vf[ks][ch] = *(const half8*)(Vb + (size_t)(ch * 16 + r) * NSP + kb0 + ks * 32 + g * 8);

        // S = Q K^T  (D-layout: row q = g*4+j, col kpos = r)
        f32x4 sa[2][4];
        #pragma unroll
        for (int qf = 0; qf < 2; ++qf)
            #pragma unroll
            for (int kh = 0; kh < 4; ++kh)
                sa[qf][kh] = __builtin_amdgcn_mfma_f32_16x16x32_f16(qa[qf], kf[kh], zero4, 0, 0, 0);

        // defer-max check (no cross-lane reduce on the fast path)
        float mx = -1e30f;
        #pragma unroll
        for (int qf = 0; qf < 2; ++qf)
            #pragma unroll
            for (int j = 0; j < 4; ++j) {
                float rm = fmaxf(fmaxf(sa[qf][0][j], sa[qf][1][j]),
                                 fmaxf(sa[qf][2][j], sa[qf][3][j]));
                mx = fmaxf(mx, rm - m_run[qf][j]);
            }
        if (__any(mx > 8.f)) {   // slow path: true row-max update + rescale
            #pragma unroll
            for (int qf = 0; qf < 2; ++qf)
                #pragma unroll
                for (int j = 0; j < 4; ++j) {
                    float tm = fmaxf(fmaxf(sa[qf][0][j], sa[qf][1][j]),
                                     fmaxf(sa[qf][2][j], sa[qf][3][j]));
                    tm = fmaxf(tm, __shfl_xor(tm, 1));
                    tm = fmaxf(tm, __shfl_xor(tm, 2));
                    tm = fmaxf(tm, __shfl_xor(tm, 4));
                    tm = fmaxf(tm, __shfl_xor(tm, 8));
                    float mn = fmaxf(m_run[qf][j], tm);
                    float sc = __expf(m_run[qf][j] - mn);
                    l_run[qf][j] *= sc;
                    yacc[qf][0][j] *= sc;
                    yacc[qf][1][j] *= sc;
                    m_run[qf][j] = mn;
                }
        }

        // P = exp(S - m), per-lane l accumulation, stage P tile to LDS
        #pragma unroll
        for (int qf = 0; qf < 2; ++qf)
            #pragma unroll
            for (int kh = 0; kh < 4; ++kh)
                #pragma unroll
                for (int j = 0; j < 4; ++j) {
                    float p = __expf(sa[qf][kh][j] - m_run[qf][j]);
                    l_run[qf][j] += p;
                    PB[qf * 16 + g * 4 + j][kh * 16 + r] = (_Float16)p;
                }
        __syncthreads();

        // PV: y += P V
        #pragma unroll
        for (int ks = 0; ks < 2; ++ks) {
            half8 pa[2];
            #pragma unroll
            for (int qf = 0; qf < 2; ++qf)
                pa[qf] = *(const half8*)(&PB[qf * 16 + r][ks * 32 + g * 8]);
            #pragma unroll
            for (int qf = 0; qf < 2; ++qf)
                #pragma unroll
                for (int ch = 0; ch < 2; ++ch)
                    yacc[qf][ch] = __builtin_amdgcn_mfma_f32_16x16x32_f16(
                        pa[qf], vf[ks][ch], yacc[qf][ch], 0, 0, 0);
        }
        __syncthreads();
    }

    // final row-sum reduce of l across the 16 lanes of each group
    #pragma unroll
    for (int qf = 0; qf < 2; ++qf)
        #pragma unroll
        for (int j = 0; j < 4; ++j) {
            float lv = l_run[qf][j];
            lv += __shfl_xor(lv, 1);
            lv += __shfl_xor(lv, 2);
            lv += __shfl_xor(lv, 4);
            lv += __shfl_xor(lv, 8);
            l_run[qf][j] = lv;
        }

    if (r == 0) {
        #pragma unroll
        for (int qf = 0; qf < 2; ++qf)
            #pragma unroll
            for (int j = 0; j < 4; ++j) {
                int row = t * 32 + qf * 16 + g * 4 + j;
                size_t base = ((size_t)(s * NB + b) * NSP + row) * 2;
                ML[base + 0] = m_run[qf][j];
                ML[base + 1] = l_run[qf][j];
            }
    }
    #pragma unroll
    for (int qf = 0; qf < 2; ++qf)
        #pragma unroll
        for (int ch = 0; ch < 2; ++ch)
            #pragma unroll
            for (int j = 0; j < 4; ++j) {
                int row = t * 32 + qf * 16 + g * 4 + j;
                YU[((size_t)(s * NB + b) * NSP + row) * ICH + ch * 16 + r] = yacc[qf][ch][j];
            }
}

// ---------------------------------------------------------------------------
// Kernel 3: combine k-splits, normalize, fused W 1x1 projection + bias + residual.
// grid = 200 blocks (b(2) x 100 row-groups of 64), 256 threads.
// ---------------------------------------------------------------------------
__global__ __launch_bounds__(256) void nlb_combine_kernel(
    const float* __restrict__ YU, const float* __restrict__ ML,
    const float* __restrict__ W_w, const float* __restrict__ W_b,
    const float* __restrict__ x, float* __restrict__ out)
{
    const int bid = blockIdx.x;
    const int b = bid / 100;
    const int rowbase = (bid % 100) * 64;

    __shared__ float ylds[64][33];
    __shared__ float wwl[CIN * ICH];

    const int tid = threadIdx.x;
    for (int e = tid; e < CIN * ICH; e += 256) wwl[e] = W_w[e];

    #pragma unroll
    for (int i = 0; i < 8; ++i) {
        int idx = tid + i * 256;          // 0..2047 -> (row, c)
        int row = idx >> 5, c = idx & 31;
        int grow = rowbase + row;
        float m[KSPLIT], lv[KSPLIT], M = -1e30f;
        #pragma unroll
        for (int s2 = 0; s2 < KSPLIT; ++s2) {
            size_t base = ((size_t)(s2 * NB + b) * NSP + grow) * 2;
            m[s2]  = ML[base + 0];
            lv[s2] = ML[base + 1];
            M = fmaxf(M, m[s2]);
        }
        float denom = 0.f, acc = 0.f;
        #pragma unroll
        for (int s2 = 0; s2 < KSPLIT; ++s2) {
            float e2 = __expf(m[s2] - M);
            denom += lv[s2] * e2;
            acc += YU[((size_t)(s2 * NB + b) * NSP + grow) * ICH + c] * e2;
        }
        ylds[row][c] = acc / denom;
    }
    __syncthreads();

    const int row = tid & 63;
    const int o0  = tid >> 6;             // 0..3
    #pragma unroll
    for (int k = 0; k < 16; ++k) {
        int o = o0 * 16 + k;
        size_t gi = (size_t)(b * CIN + o) * NSP + rowbase + row;
        float accv = W_b[o] + x[gi];
        #pragma unroll
        for (int c = 0; c < ICH; ++c) accv += wwl[o * ICH + c] * ylds[row][c];
        out[gi] = accv;
    }
}

// ---------------------------------------------------------------------------
extern "C" void kernel_launch(void* const* d_in, const int* in_sizes, int n_in,
                              void* d_out, int out_size, void* d_ws, size_t ws_size,
                              hipStream_t stream) {
    const float* x        = (const float*)d_in[0];
    const float* x_t      = (const float*)d_in[1];
    const float* g_w      = (const float*)d_in[2];
    const float* g_b      = (const float*)d_in[3];
    const float* W_w      = (const float*)d_in[4];
    const float* W_b      = (const float*)d_in[5];
    const float* shared_w = (const float*)d_in[6];
    const float* shared_b = (const float*)d_in[7];
    float* out = (float*)d_out;

    char* ws = (char*)d_ws;
    _Float16* Q   = (_Float16*)(ws);                   //   819,200 B
    _Float16* K   = (_Float16*)(ws + 819200);          //   819,200 B
    _Float16* Vt  = (_Float16*)(ws + 1638400);         //   819,200 B
    float*    YU  = (float*)(ws + 2457600);            // 8,192,000 B
    float*    ML  = (float*)(ws + 10649600);           //   512,000 B
    _Float16* W9f = (_Float16*)(ws + 11161600);        //    36,864 B
    _Float16* GWf = (_Float16*)(ws + 11198464);        //     4,096 B

    hipLaunchKernelGGL(nlb_prep_kernel, dim3(80), dim3(256), 0, stream,
                       shared_w, g_w, W9f, GWf);
    hipLaunchKernelGGL(nlb_conv_mfma_kernel, dim3(320), dim3(128), 0, stream,
                       x, x_t, W9f, GWf, shared_b, g_b, Q, K, Vt);
    hipLaunchKernelGGL(nlb_attn_kernel, dim3(2000), dim3(64), 0, stream,
                       Q, K, Vt, YU, ML);
    hipLaunchKernelGGL(nlb_combine_kernel, dim3(200), dim3(256), 0, stream,
                       YU, ML, W_w, W_b, x, out);
}